// Round 1
// baseline (21.597 us; speedup 1.0000x reference)
//
#include <hip/hip_runtime.h>

// Problem constants (match reference).
constexpr int VOCAB    = 32000;
constexpr int MAX_LEN  = 64;
constexpr int HIDDEN   = 96;
constexpr int BATCH    = 4096;

// Launch geometry: 4 batch rows per block, 48 threads/row (float2 each).
constexpr int ROWS_PER_BLOCK = 4;
constexpr int TPR   = HIDDEN / 2;              // 48 threads per row
constexpr int BLOCK = ROWS_PER_BLOCK * TPR;    // 192 threads (3 waves)

__global__ __launch_bounds__(BLOCK) void posmlp_kernel(
    const int*   __restrict__ ids,   // [BATCH, MAX_LEN]
    const float* __restrict__ W1,    // [MAX_LEN, VOCAB, HIDDEN]
    const float* __restrict__ b1,    // [HIDDEN]
    const float* __restrict__ W2,    // [HIDDEN, 2]
    const float* __restrict__ b2,    // [2]
    float*       __restrict__ out)   // [BATCH, 2]
{
    __shared__ int   s_ids[ROWS_PER_BLOCK * MAX_LEN];
    __shared__ float s_red[ROWS_PER_BLOCK][TPR][2];

    const int tid  = threadIdx.x;
    const int row0 = blockIdx.x * ROWS_PER_BLOCK;

    // Stage this block's ids into LDS (coalesced, done once).
    for (int i = tid; i < ROWS_PER_BLOCK * MAX_LEN; i += BLOCK)
        s_ids[i] = ids[row0 * MAX_LEN + i];
    __syncthreads();

    const int r = tid / TPR;        // row within block
    const int c = tid % TPR;        // float2 column within hidden dim
    const int* my_ids = &s_ids[r * MAX_LEN];

    // Gather-sum over positions. Each 48-lane group reads one contiguous
    // 384 B W1 row per position (8 B/lane, aligned: row base is 384 B
    // multiple, +8*c stays 8 B aligned).
    float ax = 0.f, ay = 0.f;
#pragma unroll 8
    for (int p = 0; p < MAX_LEN; ++p) {
        const int id = my_ids[p];
        const float2 v = *reinterpret_cast<const float2*>(
            W1 + (size_t)(p * VOCAB + id) * HIDDEN + 2 * c);
        ax += v.x;
        ay += v.y;
    }

    // Bias + ReLU.
    const float2 bb = *reinterpret_cast<const float2*>(b1 + 2 * c);
    const float hx = fmaxf(ax + bb.x, 0.f);
    const float hy = fmaxf(ay + bb.y, 0.f);

    // Partial products for the 96x2 matvec.
    const float w00 = W2[(2 * c) * 2 + 0], w01 = W2[(2 * c) * 2 + 1];
    const float w10 = W2[(2 * c + 1) * 2 + 0], w11 = W2[(2 * c + 1) * 2 + 1];
    s_red[r][c][0] = hx * w00 + hy * w10;
    s_red[r][c][1] = hx * w01 + hy * w11;
    __syncthreads();

    // Final reduction: 8 threads (4 rows x 2 outputs), 48 adds each.
    if (tid < ROWS_PER_BLOCK * 2) {
        const int rr = tid >> 1, j = tid & 1;
        float s = 0.f;
#pragma unroll
        for (int k = 0; k < TPR; ++k) s += s_red[rr][k][j];
        out[(row0 + rr) * 2 + j] = s + b2[j];
    }
}

extern "C" void kernel_launch(void* const* d_in, const int* in_sizes, int n_in,
                              void* d_out, int out_size, void* d_ws, size_t ws_size,
                              hipStream_t stream) {
    const int*   ids = (const int*)d_in[0];
    const float* W1  = (const float*)d_in[1];
    const float* b1  = (const float*)d_in[2];
    const float* W2  = (const float*)d_in[3];
    const float* b2  = (const float*)d_in[4];
    float* out = (float*)d_out;

    posmlp_kernel<<<dim3(BATCH / ROWS_PER_BLOCK), dim3(BLOCK), 0, stream>>>(
        ids, W1, b1, W2, b2, out);
}

// Round 2
// 21.311 us; speedup vs baseline: 1.0134x; 1.0134x over previous
//
#include <hip/hip_runtime.h>

// Problem constants (match reference).
constexpr int VOCAB    = 32000;
constexpr int MAX_LEN  = 64;
constexpr int HIDDEN   = 96;
constexpr int BATCH    = 4096;

// Geometry: 4 batch rows/block, positions split 2-way, 48 threads per
// (row, pos-half) reading float2 each -> 384 threads (6 waves)/block.
constexpr int POS_SPLIT      = 2;
constexpr int POS_PER        = MAX_LEN / POS_SPLIT;   // 32
constexpr int ROWS_PER_BLOCK = 4;
constexpr int TPR            = HIDDEN / 2;            // 48
constexpr int BLOCK          = ROWS_PER_BLOCK * POS_SPLIT * TPR;  // 384

__global__ __launch_bounds__(BLOCK) void posmlp_kernel(
    const int*   __restrict__ ids,   // [BATCH, MAX_LEN]
    const float* __restrict__ W1,    // [MAX_LEN, VOCAB, HIDDEN]
    const float* __restrict__ b1,    // [HIDDEN]
    const float* __restrict__ W2,    // [HIDDEN, 2]
    const float* __restrict__ b2,    // [2]
    float*       __restrict__ out)   // [BATCH, 2]
{
    __shared__ int    s_ids[ROWS_PER_BLOCK * MAX_LEN];
    __shared__ float2 s_acc[ROWS_PER_BLOCK][POS_SPLIT][TPR];
    __shared__ float  s_red[ROWS_PER_BLOCK][TPR][2];

    const int tid  = threadIdx.x;
    const int row0 = blockIdx.x * ROWS_PER_BLOCK;

    // Stage this block's ids into LDS (coalesced, once).
    for (int i = tid; i < ROWS_PER_BLOCK * MAX_LEN; i += BLOCK)
        s_ids[i] = ids[row0 * MAX_LEN + i];
    __syncthreads();

    const int grp = tid / TPR;   // 0..7 = (row, half)
    const int c   = tid % TPR;   // float2 column within hidden dim
    const int r   = grp >> 1;
    const int h   = grp & 1;
    const int* my_ids = &s_ids[r * MAX_LEN + h * POS_PER];

    // Gather-sum over this thread's 32 positions. Each 48-lane group reads
    // one contiguous, 128B-aligned 384 B W1 row per position.
    float ax = 0.f, ay = 0.f;
#pragma unroll 16
    for (int p = 0; p < POS_PER; ++p) {
        const int id = my_ids[p];
        const float2 v = *reinterpret_cast<const float2*>(
            W1 + (size_t)((h * POS_PER + p) * VOCAB + id) * HIDDEN + 2 * c);
        ax += v.x;
        ay += v.y;
    }
    s_acc[r][h][c] = make_float2(ax, ay);
    __syncthreads();

    // Half 0 combines both halves, applies bias+ReLU, writes matvec partials.
    if (h == 0) {
        const float2 o = s_acc[r][1][c];
        ax += o.x;
        ay += o.y;
        const float2 bb = *reinterpret_cast<const float2*>(b1 + 2 * c);
        const float hx = fmaxf(ax + bb.x, 0.f);
        const float hy = fmaxf(ay + bb.y, 0.f);
        const float w00 = W2[(2 * c) * 2 + 0], w01 = W2[(2 * c) * 2 + 1];
        const float w10 = W2[(2 * c + 1) * 2 + 0], w11 = W2[(2 * c + 1) * 2 + 1];
        s_red[r][c][0] = hx * w00 + hy * w10;
        s_red[r][c][1] = hx * w01 + hy * w11;
    }
    __syncthreads();

    // Final reduction: 8 threads (4 rows x 2 outputs), 48 adds each.
    if (tid < ROWS_PER_BLOCK * 2) {
        const int rr = tid >> 1, j = tid & 1;
        float s = 0.f;
#pragma unroll
        for (int k = 0; k < TPR; ++k) s += s_red[rr][k][j];
        out[(row0 + rr) * 2 + j] = s + b2[j];
    }
}

extern "C" void kernel_launch(void* const* d_in, const int* in_sizes, int n_in,
                              void* d_out, int out_size, void* d_ws, size_t ws_size,
                              hipStream_t stream) {
    const int*   ids = (const int*)d_in[0];
    const float* W1  = (const float*)d_in[1];
    const float* b1  = (const float*)d_in[2];
    const float* W2  = (const float*)d_in[3];
    const float* b2  = (const float*)d_in[4];
    float* out = (float*)d_out;

    posmlp_kernel<<<dim3(BATCH / ROWS_PER_BLOCK), dim3(BLOCK), 0, stream>>>(
        ids, W1, b1, W2, b2, out);
}